// Round 1
// baseline (475.479 us; speedup 1.0000x reference)
//
#include <hip/hip_runtime.h>
#include <math.h>

// Problem constants (B,N,K,C,H,W) = (2,8,8,256,96,96)
constexpr int Bc = 2, Nc = 8, Kc = 8, Cc = 256, HWc = 96 * 96;   // HW = 9216
constexpr int BN = Bc * Nc;                                       // 16
constexpr int HW2 = HWc / 2;                                      // 4608 float2
constexpr float ALPHA = 0.3f;
constexpr float SIM_HIGH = 0.8f, SIM_LOW = 0.3f;

// ---- k3 geometry: intra-wave channel split ---------------------------------
constexpr int CG = 8;                  // channel groups per wave (lane>>3)
constexpr int CPG = Cc / CG;           // 32 channels per lane
constexpr int PPW = 64 / CG;           // 8 float2 positions per wave (lane&7)
constexpr int PPB = PPW * 4;           // 32 float2 per 4-wave block
constexpr int TILES = HW2 / PPB;       // 144 tiles per (b,n)
constexpr int CGSTRIDE = CPG * 8 + 4;  // 260 floats; 260%32==4 -> the 8
                                       // per-wave ds_read_b128 addrs hit
                                       // disjoint bank quads (conflict-free)

// ---------------- reduction helpers ----------------------------------------
__device__ __forceinline__ float wred_sum_all(float v) {   // butterfly, all lanes
#pragma unroll
  for (int o = 32; o > 0; o >>= 1) v += __shfl_xor(v, o, 64);
  return v;
}
__device__ __forceinline__ float wred_sum(float v) {
#pragma unroll
  for (int o = 32; o > 0; o >>= 1) v += __shfl_down(v, o, 64);
  return v;
}
__device__ __forceinline__ float wred_max(float v) {
#pragma unroll
  for (int o = 32; o > 0; o >>= 1) v = fmaxf(v, __shfl_down(v, o, 64));
  return v;
}
__device__ __forceinline__ float bred_sum(float v, float* sc) {
  int lane = threadIdx.x & 63, wid = threadIdx.x >> 6;
  v = wred_sum(v);
  __syncthreads();
  if (lane == 0) sc[wid] = v;
  __syncthreads();
  return sc[0] + sc[1] + sc[2] + sc[3];
}
__device__ __forceinline__ float bred_max(float v, float* sc) {
  int lane = threadIdx.x & 63, wid = threadIdx.x >> 6;
  v = wred_max(v);
  __syncthreads();
  if (lane == 0) sc[wid] = v;
  __syncthreads();
  return fmaxf(fmaxf(sc[0], sc[1]), fmaxf(sc[2], sc[3]));
}

// ---------------- K1: per-(b,n,c) sums of value and value*mask -------------
__global__ __launch_bounds__(256) void k1_sums(const float* __restrict__ value,
                                               const float* __restrict__ mask,
                                               float* __restrict__ sum_v,
                                               float* __restrict__ sum_vm) {
  const int bnc = blockIdx.x;      // (b*N+n)*C + c
  const int bn = bnc >> 8;
  const int tid = threadIdx.x;
  const float4* v4 = (const float4*)(value + (size_t)bnc * HWc);
  const float4* m4 = (const float4*)(mask + (size_t)bn * HWc);
  float av = 0.f, avm = 0.f;
#pragma unroll
  for (int i = 0; i < 9; ++i) {              // 9*256*4 = 9216
    float4 v = v4[i * 256 + tid];
    float4 m = m4[i * 256 + tid];
    av += v.x + v.y + v.z + v.w;
    avm += v.x * m.x + v.y * m.y + v.z * m.z + v.w * m.w;
  }
  __shared__ float sc[8];
  float rv = wred_sum(av);
  float rvm = wred_sum(avm);
  int lane = tid & 63, wid = tid >> 6;
  if (lane == 0) { sc[wid] = rv; sc[4 + wid] = rvm; }
  __syncthreads();
  if (tid == 0) {
    sum_v[bnc] = sc[0] + sc[1] + sc[2] + sc[3];
    sum_vm[bnc] = sc[4] + sc[5] + sc[6] + sc[7];
  }
}

// ---------------- K2: control logic + bank update (1 block per (b,n)) ------
// Wave-parallel: wave w owns k = w and k = w+4.
// Outputs proto_new + per-k inverse norms (bank_inv) — k3 folds the
// normalization as a scalar instead of staging a second 8KB LDS table.
__global__ __launch_bounds__(256) void k2_update(
    const float* __restrict__ mask, const float* __restrict__ proto,
    const float* __restrict__ age, const float* __restrict__ usage,
    const float* __restrict__ conf, const int* __restrict__ valid,
    const float* __restrict__ sum_v, const float* __restrict__ sum_vm,
    float* __restrict__ proto_new, float* __restrict__ bank_inv,
    float* __restrict__ validf) {
  const int bn = blockIdx.x;
  const int tid = threadIdx.x;
  const int lane = tid & 63, w = tid >> 6;
  __shared__ float sc[4];
  __shared__ float s_cand[Cc];
  __shared__ float s_sim[Kc];
  __shared__ int s_slot, s_ref, s_wr;

  // global maxima for age_n / usage_n (over all B,N,K = 128 values)
  float a = (tid < BN * Kc) ? age[tid] : -3e38f;
  float u = (tid < BN * Kc) ? usage[tid] : -3e38f;
  const float age_den = fmaxf(bred_max(a, sc), 1.0f);
  const float usage_den = fmaxf(bred_max(u, sc), 1.0f);

  // mask sum for this (b,n) — float4 vectorized
  float ms = 0.f;
  const float4* m4 = (const float4*)(mask + (size_t)bn * HWc);
  for (int i = tid; i < HWc / 4; i += 256) {
    const float4 mm = m4[i];
    ms += (mm.x + mm.y) + (mm.z + mm.w);
  }
  const float msum = bred_sum(ms, sc);
  const float denom = fmaxf(msum, 1e-6f);

  // candidate prototype (c = tid), l2-normalized
  const int c = tid;
  const float sv = sum_v[bn * Cc + c];
  const float svm = sum_vm[bn * Cc + c];
  float cand = (denom <= 1e-5f) ? (sv * (1.0f / HWc)) : (svm / denom);
  const float css = bred_sum(cand * cand, sc);
  s_cand[c] = cand / fmaxf(sqrtf(css), 1e-12f);
  __syncthreads();

  const float4* cand4 = (const float4*)s_cand;
  const float4 c4 = cand4[lane];

  // sims: wave w handles k = w, w+4 (no block syncs)
#pragma unroll
  for (int kk = 0; kk < 2; ++kk) {
    const int k = w + kk * 4;
    const float4 p4 = ((const float4*)(proto + ((size_t)bn * Kc + k) * Cc))[lane];
    const float pss = wred_sum_all(p4.x * p4.x + p4.y * p4.y + p4.z * p4.z + p4.w * p4.w);
    const float pd  = wred_sum_all(p4.x * c4.x + p4.y * c4.y + p4.z * c4.z + p4.w * c4.w);
    if (lane == 0)
      s_sim[k] = (valid[bn * Kc + k] != 0) ? (pd / fmaxf(sqrtf(pss), 1e-12f)) : -1.0f;
  }
  __syncthreads();

  if (tid == 0) {
    bool anyv = false;
    for (int k = 0; k < Kc; ++k) anyv = anyv || (valid[bn * Kc + k] != 0);
    int tslot = 0; float best = s_sim[0];
    for (int k = 1; k < Kc; ++k)
      if (s_sim[k] > best) { best = s_sim[k]; tslot = k; }   // first max
    const float max_sim = anyv ? best : -1.0f;
    const int action = (!anyv) ? 3 : (max_sim >= SIM_HIGH ? 1 : (max_sim >= SIM_LOW ? 0 : 3));
    int victim = 0; float vb = -3e38f;
    for (int k = 0; k < Kc; ++k) {
      const float s = age[bn * Kc + k] / age_den + (1.f - usage[bn * Kc + k] / usage_den) +
                      (1.f - conf[bn * Kc + k]);
      if (s > vb) { vb = s; victim = k; }
    }
    int fe = 0; bool hasE = false;
    for (int k = 0; k < Kc; ++k)
      if (valid[bn * Kc + k] == 0) { fe = k; hasE = true; break; }
    const int spawn = hasE ? fe : victim;
    s_slot = (action == 1) ? tslot : spawn;
    s_ref = (action == 1);
    s_wr = (action == 3);
  }
  __syncthreads();

  // bank update + per-k inverse norm (wave-parallel, branches wave-uniform)
#pragma unroll
  for (int kk = 0; kk < 2; ++kk) {
    const int k = w + kk * 4;
    const float4 p4 = ((const float4*)(proto + ((size_t)bn * Kc + k) * Cc))[lane];
    float4 pn;
    if (k == s_slot && s_ref) {
      float4 t;
      t.x = (1.0f - ALPHA) * p4.x + ALPHA * c4.x;
      t.y = (1.0f - ALPHA) * p4.y + ALPHA * c4.y;
      t.z = (1.0f - ALPHA) * p4.z + ALPHA * c4.z;
      t.w = (1.0f - ALPHA) * p4.w + ALPHA * c4.w;
      const float tss = wred_sum_all(t.x * t.x + t.y * t.y + t.z * t.z + t.w * t.w);
      const float inv = 1.0f / fmaxf(sqrtf(tss), 1e-12f);
      pn.x = t.x * inv; pn.y = t.y * inv; pn.z = t.z * inv; pn.w = t.w * inv;
    } else if (k == s_slot && s_wr) {
      pn = c4;
    } else {
      pn = p4;
    }
    ((float4*)(proto_new + ((size_t)bn * Kc + k) * Cc))[lane] = pn;
    const float bss = wred_sum_all(pn.x * pn.x + pn.y * pn.y + pn.z * pn.z + pn.w * pn.w);
    if (lane == 0) bank_inv[bn * Kc + k] = 1.0f / fmaxf(sqrtf(bss), 1e-12f);
  }
  if (tid < Kc) {
    const int k = tid;
    const int vn = (valid[bn * Kc + k] != 0) || (s_wr && k == s_slot);
    validf[bn * Kc + k] = vn ? 1.0f : 0.0f;
  }
}

// ---------------- K3: readout (softmax-attention blend) --------------------
// Intra-wave channel split: lane = (cg<<3)|pl; cg in [0,8) owns 32 channels,
// pl in [0,8) owns one float2 position. The 256-channel dot completes with
// 3 shfl_xor rounds — no cross-wave LDS reduce, no s_part/s_attn, softmax
// fully in registers on all 64 lanes, no block sync after staging.
// LDS = 8.4KB -> 8 blocks/CU (wave-capped). Grid = BN*144 = 2304 blocks.
__global__ __launch_bounds__(256, 8) void k3_readout(
    const float* __restrict__ value, const float* __restrict__ frame,
    const float* __restrict__ proto_new, const float* __restrict__ bank_inv,
    const float* __restrict__ validf, const float* __restrict__ pgp,
    const float* __restrict__ fgp, float* __restrict__ out) {
  const int bn = blockIdx.x / TILES;
  const int tile = blockIdx.x % TILES;
  const int b = bn >> 3;
  const int tid = threadIdx.x;
  const int lane = tid & 63, w = tid >> 6;
  const int cg = lane >> 3;                 // channel group 0..7
  const int pl = lane & 7;                  // position-in-wave 0..7
  const int p2 = tile * PPB + w * PPW + pl; // float2 index within HW2

  __shared__ float s_pn[CG * CGSTRIDE];     // [cg][32c x 8k (+4 pad)]  8.3KB
  __shared__ float s_inv[Kc];
  __shared__ float s_vld[Kc];

  // stage proto_new transposed to [c][k] with per-cg pad (coalesced reads)
  const float* psrc = proto_new + (size_t)bn * Kc * Cc;
  for (int i = tid; i < Kc * Cc; i += 256) {
    const int k = i >> 8, c = i & 255;
    s_pn[(c >> 5) * CGSTRIDE + (c & 31) * 8 + k] = psrc[i];
  }
  if (tid < Kc) {
    s_inv[tid] = bank_inv[bn * Kc + tid];
    s_vld[tid] = validf[bn * Kc + tid];
  }
  __syncthreads();

  const float pg = pgp[0], fg = fgp[0];
  const float2* v2 = (const float2*)(value + (size_t)bn * Cc * HWc);
  const float2* f2 = (const float2*)(frame + (size_t)b * Cc * HWc);
  float2* o2 = (float2*)(out + (size_t)bn * Cc * HWc);
  const size_t base = (size_t)(cg * CPG) * HW2 + p2;
  const float4* pn4 = (const float4*)(s_pn + cg * CGSTRIDE);

  // ---- pass 1: partial dots + partial ||v||^2 over this lane's 32 c -------
  float ss0 = 0.f, ss1 = 0.f;
  float d0[8], d1[8];
#pragma unroll
  for (int k = 0; k < 8; ++k) { d0[k] = 0.f; d1[k] = 0.f; }

#pragma unroll 4
  for (int i = 0; i < CPG; ++i) {
    const float2 v = v2[base + (size_t)i * HW2];
    const float4 ba = pn4[i * 2 + 0];       // conflict-free (pad stride)
    const float4 bb = pn4[i * 2 + 1];
    ss0 += v.x * v.x; ss1 += v.y * v.y;
    d0[0] += ba.x * v.x; d0[1] += ba.y * v.x; d0[2] += ba.z * v.x; d0[3] += ba.w * v.x;
    d0[4] += bb.x * v.x; d0[5] += bb.y * v.x; d0[6] += bb.z * v.x; d0[7] += bb.w * v.x;
    d1[0] += ba.x * v.y; d1[1] += ba.y * v.y; d1[2] += ba.z * v.y; d1[3] += ba.w * v.y;
    d1[4] += bb.x * v.y; d1[5] += bb.y * v.y; d1[6] += bb.z * v.y; d1[7] += bb.w * v.y;
  }

  // ---- in-register reduce across the 8 channel groups (lane bits 3,4,5) ---
#pragma unroll
  for (int k = 0; k < 8; ++k) {
    d0[k] += __shfl_xor(d0[k], 8, 64);
    d0[k] += __shfl_xor(d0[k], 16, 64);
    d0[k] += __shfl_xor(d0[k], 32, 64);
    d1[k] += __shfl_xor(d1[k], 8, 64);
    d1[k] += __shfl_xor(d1[k], 16, 64);
    d1[k] += __shfl_xor(d1[k], 32, 64);
  }
  ss0 += __shfl_xor(ss0, 8, 64); ss0 += __shfl_xor(ss0, 16, 64); ss0 += __shfl_xor(ss0, 32, 64);
  ss1 += __shfl_xor(ss1, 8, 64); ss1 += __shfl_xor(ss1, 16, 64); ss1 += __shfl_xor(ss1, 32, 64);

  // ---- softmax (redundant across the 8 cg lanes — all lanes busy) ---------
  const float rn0 = 1.0f / fmaxf(sqrtf(ss0), 1e-12f);
  const float rn1 = 1.0f / fmaxf(sqrtf(ss1), 1e-12f);
  float m0 = -3e38f, m1 = -3e38f;
#pragma unroll
  for (int k = 0; k < 8; ++k) {
    const float sc = s_inv[k];               // bank norm folded as scalar
    d0[k] *= sc * rn0;
    d1[k] *= sc * rn1;
    if (s_vld[k] > 0.5f) { m0 = fmaxf(m0, d0[k]); m1 = fmaxf(m1, d1[k]); }
  }
  float sum0 = 0.f, sum1 = 0.f;
#pragma unroll
  for (int k = 0; k < 8; ++k) {
    d0[k] = (s_vld[k] > 0.5f) ? __expf(d0[k] - m0) : 0.f;
    d1[k] = (s_vld[k] > 0.5f) ? __expf(d1[k] - m1) : 0.f;
    sum0 += d0[k]; sum1 += d1[k];
  }
  const float inv0 = (sum0 > 0.f) ? 1.0f / sum0 : 0.f;   // no valid -> attn 0
  const float inv1 = (sum1 > 0.f) ? 1.0f / sum1 : 0.f;
#pragma unroll
  for (int k = 0; k < 8; ++k) { d0[k] *= inv0; d1[k] *= inv1; }

  // ---- pass 2: blend this lane's 32 channels (re-read is L2/L3-hot) -------
#pragma unroll 4
  for (int i = 0; i < CPG; ++i) {
    const float2 v = v2[base + (size_t)i * HW2];
    const float2 f = f2[base + (size_t)i * HW2];
    const float4 pa = pn4[i * 2 + 0];
    const float4 pb = pn4[i * 2 + 1];
    const float pm0 = d0[0] * pa.x + d0[1] * pa.y + d0[2] * pa.z + d0[3] * pa.w +
                      d0[4] * pb.x + d0[5] * pb.y + d0[6] * pb.z + d0[7] * pb.w;
    const float pm1 = d1[0] * pa.x + d1[1] * pa.y + d1[2] * pa.z + d1[3] * pa.w +
                      d1[4] * pb.x + d1[5] * pb.y + d1[6] * pb.z + d1[7] * pb.w;
    float2 o;
    o.x = v.x + pg * pm0 + fg * f.x;
    o.y = v.y + pg * pm1 + fg * f.y;
    o2[base + (size_t)i * HW2] = o;
  }
}

// ---------------- launch ---------------------------------------------------
extern "C" void kernel_launch(void* const* d_in, const int* in_sizes, int n_in,
                              void* d_out, int out_size, void* d_ws, size_t ws_size,
                              hipStream_t stream) {
  const float* value = (const float*)d_in[0];
  const float* frame = (const float*)d_in[1];
  const float* mask  = (const float*)d_in[2];
  const float* proto = (const float*)d_in[3];
  const float* age   = (const float*)d_in[4];
  const float* usage = (const float*)d_in[5];
  const float* conf  = (const float*)d_in[6];
  // d_in[7..10] = W1,b1,W2,b2 — dead code in the reference (logits unused)
  const float* pg = (const float*)d_in[11];
  const float* fg = (const float*)d_in[12];
  const int* valid = (const int*)d_in[13];
  float* out = (float*)d_out;

  float* w = (float*)d_ws;
  float* sum_v     = w;                  // BN*Cc      = 4096
  float* sum_vm    = w + 4096;           // BN*Cc      = 4096
  float* proto_new = w + 8192;           // BN*Kc*Cc   = 32768
  float* bank_inv  = w + 40960;          // BN*Kc      = 128
  float* validf    = w + 41088;          // BN*Kc      = 128

  hipLaunchKernelGGL(k1_sums, dim3(BN * Cc), dim3(256), 0, stream,
                     value, mask, sum_v, sum_vm);
  hipLaunchKernelGGL(k2_update, dim3(BN), dim3(256), 0, stream,
                     mask, proto, age, usage, conf, valid, sum_v, sum_vm,
                     proto_new, bank_inv, validf);
  hipLaunchKernelGGL(k3_readout, dim3(BN * TILES), dim3(256), 0, stream,
                     value, frame, proto_new, bank_inv, validf, pg, fg, out);
}

// Round 2
// 353.980 us; speedup vs baseline: 1.3432x; 1.3432x over previous
//
#include <hip/hip_runtime.h>
#include <math.h>

// Problem constants (B,N,K,C,H,W) = (2,8,8,256,96,96)
constexpr int Bc = 2, Nc = 8, Kc = 8, Cc = 256, HWc = 96 * 96;   // HW = 9216
constexpr int BN = Bc * Nc;                                       // 16
constexpr int HW2 = HWc / 2;                                      // 4608 float2
constexpr float ALPHA = 0.3f;
constexpr float SIM_HIGH = 0.8f, SIM_LOW = 0.3f;
constexpr int TILES = 72;              // 64 float2 positions per block

// ---------------- reduction helpers ----------------------------------------
__device__ __forceinline__ float wred_sum_all(float v) {   // butterfly, all lanes
#pragma unroll
  for (int o = 32; o > 0; o >>= 1) v += __shfl_xor(v, o, 64);
  return v;
}
__device__ __forceinline__ float wred_sum(float v) {
#pragma unroll
  for (int o = 32; o > 0; o >>= 1) v += __shfl_down(v, o, 64);
  return v;
}
__device__ __forceinline__ float wred_max(float v) {
#pragma unroll
  for (int o = 32; o > 0; o >>= 1) v = fmaxf(v, __shfl_down(v, o, 64));
  return v;
}
__device__ __forceinline__ float bred_sum(float v, float* sc) {
  int lane = threadIdx.x & 63, wid = threadIdx.x >> 6;
  v = wred_sum(v);
  __syncthreads();
  if (lane == 0) sc[wid] = v;
  __syncthreads();
  return sc[0] + sc[1] + sc[2] + sc[3];
}
__device__ __forceinline__ float bred_max(float v, float* sc) {
  int lane = threadIdx.x & 63, wid = threadIdx.x >> 6;
  v = wred_max(v);
  __syncthreads();
  if (lane == 0) sc[wid] = v;
  __syncthreads();
  return fmaxf(fmaxf(sc[0], sc[1]), fmaxf(sc[2], sc[3]));
}

// broadcast lane c0's value of x to all lanes as a wave-uniform (SGPR) float
__device__ __forceinline__ float lane_bcast(float x, int c0) {
  return __int_as_float(__builtin_amdgcn_readlane(__float_as_int(x), c0));
}

// ---------------- K1: per-(b,n,c) sums of value and value*mask -------------
__global__ __launch_bounds__(256) void k1_sums(const float* __restrict__ value,
                                               const float* __restrict__ mask,
                                               float* __restrict__ sum_v,
                                               float* __restrict__ sum_vm) {
  const int bnc = blockIdx.x;      // (b*N+n)*C + c
  const int bn = bnc >> 8;
  const int tid = threadIdx.x;
  const float4* v4 = (const float4*)(value + (size_t)bnc * HWc);
  const float4* m4 = (const float4*)(mask + (size_t)bn * HWc);
  float av = 0.f, avm = 0.f;
#pragma unroll
  for (int i = 0; i < 9; ++i) {              // 9*256*4 = 9216
    float4 v = v4[i * 256 + tid];
    float4 m = m4[i * 256 + tid];
    av += v.x + v.y + v.z + v.w;
    avm += v.x * m.x + v.y * m.y + v.z * m.z + v.w * m.w;
  }
  __shared__ float sc[8];
  float rv = wred_sum(av);
  float rvm = wred_sum(avm);
  int lane = tid & 63, wid = tid >> 6;
  if (lane == 0) { sc[wid] = rv; sc[4 + wid] = rvm; }
  __syncthreads();
  if (tid == 0) {
    sum_v[bnc] = sc[0] + sc[1] + sc[2] + sc[3];
    sum_vm[bnc] = sc[4] + sc[5] + sc[6] + sc[7];
  }
}

// ---------------- K2: control logic + bank update (1 block per (b,n)) ------
// Wave-parallel: wave w owns k = w and k = w+4.
// Outputs proto_new + per-k inverse norms (bank_inv); k3 folds the
// normalization as a scalar — no normalized copy of the bank is written.
__global__ __launch_bounds__(256) void k2_update(
    const float* __restrict__ mask, const float* __restrict__ proto,
    const float* __restrict__ age, const float* __restrict__ usage,
    const float* __restrict__ conf, const int* __restrict__ valid,
    const float* __restrict__ sum_v, const float* __restrict__ sum_vm,
    float* __restrict__ proto_new, float* __restrict__ bank_inv,
    float* __restrict__ validf) {
  const int bn = blockIdx.x;
  const int tid = threadIdx.x;
  const int lane = tid & 63, w = tid >> 6;
  __shared__ float sc[4];
  __shared__ float s_cand[Cc];
  __shared__ float s_sim[Kc];
  __shared__ int s_slot, s_ref, s_wr;

  // global maxima for age_n / usage_n (over all B,N,K = 128 values)
  float a = (tid < BN * Kc) ? age[tid] : -3e38f;
  float u = (tid < BN * Kc) ? usage[tid] : -3e38f;
  const float age_den = fmaxf(bred_max(a, sc), 1.0f);
  const float usage_den = fmaxf(bred_max(u, sc), 1.0f);

  // mask sum for this (b,n) — float4 vectorized
  float ms = 0.f;
  const float4* m4 = (const float4*)(mask + (size_t)bn * HWc);
  for (int i = tid; i < HWc / 4; i += 256) {
    const float4 mm = m4[i];
    ms += (mm.x + mm.y) + (mm.z + mm.w);
  }
  const float msum = bred_sum(ms, sc);
  const float denom = fmaxf(msum, 1e-6f);

  // candidate prototype (c = tid), l2-normalized
  const int c = tid;
  const float sv = sum_v[bn * Cc + c];
  const float svm = sum_vm[bn * Cc + c];
  float cand = (denom <= 1e-5f) ? (sv * (1.0f / HWc)) : (svm / denom);
  const float css = bred_sum(cand * cand, sc);
  s_cand[c] = cand / fmaxf(sqrtf(css), 1e-12f);
  __syncthreads();

  const float4* cand4 = (const float4*)s_cand;
  const float4 c4 = cand4[lane];

  // sims: wave w handles k = w, w+4 (no block syncs)
#pragma unroll
  for (int kk = 0; kk < 2; ++kk) {
    const int k = w + kk * 4;
    const float4 p4 = ((const float4*)(proto + ((size_t)bn * Kc + k) * Cc))[lane];
    const float pss = wred_sum_all(p4.x * p4.x + p4.y * p4.y + p4.z * p4.z + p4.w * p4.w);
    const float pd  = wred_sum_all(p4.x * c4.x + p4.y * c4.y + p4.z * c4.z + p4.w * c4.w);
    if (lane == 0)
      s_sim[k] = (valid[bn * Kc + k] != 0) ? (pd / fmaxf(sqrtf(pss), 1e-12f)) : -1.0f;
  }
  __syncthreads();

  if (tid == 0) {
    bool anyv = false;
    for (int k = 0; k < Kc; ++k) anyv = anyv || (valid[bn * Kc + k] != 0);
    int tslot = 0; float best = s_sim[0];
    for (int k = 1; k < Kc; ++k)
      if (s_sim[k] > best) { best = s_sim[k]; tslot = k; }   // first max
    const float max_sim = anyv ? best : -1.0f;
    const int action = (!anyv) ? 3 : (max_sim >= SIM_HIGH ? 1 : (max_sim >= SIM_LOW ? 0 : 3));
    int victim = 0; float vb = -3e38f;
    for (int k = 0; k < Kc; ++k) {
      const float s = age[bn * Kc + k] / age_den + (1.f - usage[bn * Kc + k] / usage_den) +
                      (1.f - conf[bn * Kc + k]);
      if (s > vb) { vb = s; victim = k; }
    }
    int fe = 0; bool hasE = false;
    for (int k = 0; k < Kc; ++k)
      if (valid[bn * Kc + k] == 0) { fe = k; hasE = true; break; }
    const int spawn = hasE ? fe : victim;
    s_slot = (action == 1) ? tslot : spawn;
    s_ref = (action == 1);
    s_wr = (action == 3);
  }
  __syncthreads();

  // bank update + per-k inverse norm (wave-parallel, branches wave-uniform)
#pragma unroll
  for (int kk = 0; kk < 2; ++kk) {
    const int k = w + kk * 4;
    const float4 p4 = ((const float4*)(proto + ((size_t)bn * Kc + k) * Cc))[lane];
    float4 pn;
    if (k == s_slot && s_ref) {
      float4 t;
      t.x = (1.0f - ALPHA) * p4.x + ALPHA * c4.x;
      t.y = (1.0f - ALPHA) * p4.y + ALPHA * c4.y;
      t.z = (1.0f - ALPHA) * p4.z + ALPHA * c4.z;
      t.w = (1.0f - ALPHA) * p4.w + ALPHA * c4.w;
      const float tss = wred_sum_all(t.x * t.x + t.y * t.y + t.z * t.z + t.w * t.w);
      const float inv = 1.0f / fmaxf(sqrtf(tss), 1e-12f);
      pn.x = t.x * inv; pn.y = t.y * inv; pn.z = t.z * inv; pn.w = t.w * inv;
    } else if (k == s_slot && s_wr) {
      pn = c4;
    } else {
      pn = p4;
    }
    ((float4*)(proto_new + ((size_t)bn * Kc + k) * Cc))[lane] = pn;
    const float bss = wred_sum_all(pn.x * pn.x + pn.y * pn.y + pn.z * pn.z + pn.w * pn.w);
    if (lane == 0) bank_inv[bn * Kc + k] = 1.0f / fmaxf(sqrtf(bss), 1e-12f);
  }
  if (tid < Kc) {
    const int k = tid;
    const int vn = (valid[bn * Kc + k] != 0) || (s_wr && k == s_slot);
    validf[bn * Kc + k] = vn ? 1.0f : 0.0f;
  }
}

// ---------------- K3: readout (softmax-attention blend) --------------------
// Round-0 geometry (proven traffic): wave w owns channels [64w,64w+64) for
// the SAME 64 float2 positions; every global access is 512B contiguous per
// wave instruction (no fetch/write amplification; pass-2 re-read is L3-hot).
// Occupancy fix vs round-0: pn tables live in 8 registers per lane and are
// broadcast per-channel via v_readlane (zero LDS, zero LDS-pipe traffic);
// bank normalization folded into the bank_inv scalar; softmax computed
// redundantly by all 4 waves (each lane needs only its own position).
// LDS = s_part (18.4KB) only -> 8 blocks/CU, 100% wave cap, 1 barrier.
__global__ __launch_bounds__(256, 8) void k3_readout(
    const float* __restrict__ value, const float* __restrict__ frame,
    const float* __restrict__ proto_new, const float* __restrict__ bank_inv,
    const float* __restrict__ validf, const float* __restrict__ pgp,
    const float* __restrict__ fgp, float* __restrict__ out) {
  const int bn = blockIdx.x / TILES;
  const int tile = blockIdx.x % TILES;
  const int b = bn >> 3;
  const int tid = threadIdx.x;
  const int lane = tid & 63, w = tid >> 6;
  const int p2 = tile * 64 + lane;           // float2 index within HW2

  __shared__ float s_part[4 * 9 * 128];      // [w][8 dots + ss][128 pos] 18.4KB

  // lane l holds proto_new[bn][k][w*64+l] for all 8 k (coalesced 256B loads)
  const float* psrc = proto_new + (size_t)bn * Kc * Cc + w * 64 + lane;
  float pnr[8];
#pragma unroll
  for (int k = 0; k < 8; ++k) pnr[k] = psrc[k * Cc];

  const float pg = pgp[0], fg = fgp[0];
  const float2* v2 = (const float2*)(value + (size_t)bn * Cc * HWc);
  const float2* f2 = (const float2*)(frame + (size_t)b * Cc * HWc);
  float2* o2 = (float2*)(out + (size_t)bn * Cc * HWc);

  // ---- pass 1: dots + ||v||^2 over this wave's 64 channels ----------------
  float ss0 = 0.f, ss1 = 0.f;
  float d0[8], d1[8];
#pragma unroll
  for (int k = 0; k < 8; ++k) { d0[k] = 0.f; d1[k] = 0.f; }

#pragma unroll 8
  for (int c0 = 0; c0 < 64; ++c0) {
    const float2 v = v2[(size_t)(w * 64 + c0) * HW2 + p2];   // 512B coalesced
    ss0 += v.x * v.x; ss1 += v.y * v.y;
#pragma unroll
    for (int k = 0; k < 8; ++k) {
      const float pk = lane_bcast(pnr[k], c0);               // SGPR broadcast
      d0[k] += pk * v.x;
      d1[k] += pk * v.y;
    }
  }

  float2* sp2 = (float2*)s_part;
#pragma unroll
  for (int k = 0; k < 8; ++k)
    sp2[(w * 9 + k) * 64 + lane] = make_float2(d0[k], d1[k]);
  sp2[(w * 9 + 8) * 64 + lane] = make_float2(ss0, ss1);
  __syncthreads();

  // ---- cross-wave reduce + softmax (redundant on all 4 waves) -------------
  float a0[8], a1[8];
  {
    float dd0[9], dd1[9];
#pragma unroll
    for (int j = 0; j < 9; ++j) {
      const float2 t0 = sp2[(0 * 9 + j) * 64 + lane];
      const float2 t1 = sp2[(1 * 9 + j) * 64 + lane];
      const float2 t2 = sp2[(2 * 9 + j) * 64 + lane];
      const float2 t3 = sp2[(3 * 9 + j) * 64 + lane];
      dd0[j] = (t0.x + t1.x) + (t2.x + t3.x);
      dd1[j] = (t0.y + t1.y) + (t2.y + t3.y);
    }
    const float rn0 = 1.0f / fmaxf(sqrtf(dd0[8]), 1e-12f);
    const float rn1 = 1.0f / fmaxf(sqrtf(dd1[8]), 1e-12f);
    float m0 = -3e38f, m1 = -3e38f;
    float vldk[8];
#pragma unroll
    for (int k = 0; k < 8; ++k) {
      vldk[k] = validf[bn * Kc + k];                 // uniform, L2-hot
      const float sc = bank_inv[bn * Kc + k];        // bank norm as scalar
      dd0[k] *= sc * rn0;
      dd1[k] *= sc * rn1;
      if (vldk[k] > 0.5f) { m0 = fmaxf(m0, dd0[k]); m1 = fmaxf(m1, dd1[k]); }
    }
    float sum0 = 0.f, sum1 = 0.f;
#pragma unroll
    for (int k = 0; k < 8; ++k) {
      a0[k] = (vldk[k] > 0.5f) ? __expf(dd0[k] - m0) : 0.f;
      a1[k] = (vldk[k] > 0.5f) ? __expf(dd1[k] - m1) : 0.f;
      sum0 += a0[k]; sum1 += a1[k];
    }
    const float i0 = (sum0 > 0.f) ? 1.0f / sum0 : 0.f;   // no valid -> attn 0
    const float i1 = (sum1 > 0.f) ? 1.0f / sum1 : 0.f;
#pragma unroll
    for (int k = 0; k < 8; ++k) { a0[k] *= i0; a1[k] *= i1; }
  }

  // ---- pass 2: blend this wave's 64 channels (re-read is L3-hot) ----------
#pragma unroll 4
  for (int c0 = 0; c0 < 64; ++c0) {
    const size_t off = (size_t)(w * 64 + c0) * HW2 + p2;
    const float2 v = v2[off];
    const float2 f = f2[off];
    float pm0 = 0.f, pm1 = 0.f;
#pragma unroll
    for (int k = 0; k < 8; ++k) {
      const float pk = lane_bcast(pnr[k], c0);
      pm0 += a0[k] * pk;
      pm1 += a1[k] * pk;
    }
    float2 o;
    o.x = v.x + pg * pm0 + fg * f.x;
    o.y = v.y + pg * pm1 + fg * f.y;
    o2[off] = o;                                              // 512B coalesced
  }
}

// ---------------- launch ---------------------------------------------------
extern "C" void kernel_launch(void* const* d_in, const int* in_sizes, int n_in,
                              void* d_out, int out_size, void* d_ws, size_t ws_size,
                              hipStream_t stream) {
  const float* value = (const float*)d_in[0];
  const float* frame = (const float*)d_in[1];
  const float* mask  = (const float*)d_in[2];
  const float* proto = (const float*)d_in[3];
  const float* age   = (const float*)d_in[4];
  const float* usage = (const float*)d_in[5];
  const float* conf  = (const float*)d_in[6];
  // d_in[7..10] = W1,b1,W2,b2 — dead code in the reference (logits unused)
  const float* pg = (const float*)d_in[11];
  const float* fg = (const float*)d_in[12];
  const int* valid = (const int*)d_in[13];
  float* out = (float*)d_out;

  float* w = (float*)d_ws;
  float* sum_v     = w;                  // BN*Cc      = 4096
  float* sum_vm    = w + 4096;           // BN*Cc      = 4096
  float* proto_new = w + 8192;           // BN*Kc*Cc   = 32768
  float* bank_inv  = w + 40960;          // BN*Kc      = 128
  float* validf    = w + 41088;          // BN*Kc      = 128

  hipLaunchKernelGGL(k1_sums, dim3(BN * Cc), dim3(256), 0, stream,
                     value, mask, sum_v, sum_vm);
  hipLaunchKernelGGL(k2_update, dim3(BN), dim3(256), 0, stream,
                     mask, proto, age, usage, conf, valid, sum_v, sum_vm,
                     proto_new, bank_inv, validf);
  hipLaunchKernelGGL(k3_readout, dim3(BN * TILES), dim3(256), 0, stream,
                     value, frame, proto_new, bank_inv, validf, pg, fg, out);
}